// Round 8
// baseline (291.591 us; speedup 1.0000x reference)
//
#include <hip/hip_runtime.h>
#include <math.h>

constexpr int DIN = 256;   // input dim
constexpr int H   = 4;     // heads
constexpr int O   = 64;    // out dim per head
constexpr int HO  = H * O; // 256
constexpr int AWS = 2 * O + 1; // aw row stride = 129

typedef __bf16 bf16x8 __attribute__((ext_vector_type(8)));
typedef float  f32x4  __attribute__((ext_vector_type(4)));

__device__ __forceinline__ float bf2f(unsigned short u) {
    union { unsigned int i; float f; } c;
    c.i = ((unsigned int)u) << 16;
    return c.f;
}

// ---------------------------------------------------------------------------
// Prep: blocks [0,256): Bt[n][k] = Ws[h=n>>6][k][o=n&63] as bf16.
//       blocks [256,...): cnt[i] = 0.
// ---------------------------------------------------------------------------
__global__ __launch_bounds__(256) void k_prep(const float* __restrict__ Ws,
    __bf16* __restrict__ Bt, int* __restrict__ cnt, int N)
{
    const int b = blockIdx.x;
    if (b < 256) {
        const int i = b * 256 + threadIdx.x;
        const int k = i & 255;
        const int n = i >> 8;
        Bt[n * 256 + k] = (__bf16)Ws[(n >> 6) * (DIN * O) + k * O + (n & 63)];
    } else {
        const int i = (b - 256) * 256 + threadIdx.x;
        if (i < N) cnt[i] = 0;
    }
}

// ---------------------------------------------------------------------------
// Histogram by src; rank[e] = arrival order within src row. No LDS.
// ---------------------------------------------------------------------------
__global__ __launch_bounds__(256) void k_hist(const int* __restrict__ idx, int E,
    int* __restrict__ cnt, int* __restrict__ rank)
{
    const int e = blockIdx.x * 256 + threadIdx.x;
    if (e < E) rank[e] = atomicAdd(&cnt[idx[e]], 1);
}

// ---------------------------------------------------------------------------
// LDS-free MFMA GEMM: F[n,t] = x[n,:] @ Bt[t,:]^T + bs[t] (bf16 out).
// A-frags (m=lane&15, k=quad*8+j) loaded straight from x (L3-resident),
// converted fp32->bf16 in-register. B-frags from Bt (L2-hot, 128 KB).
// No LDS, no barriers. Fused epilogue -> a_sT/a_dT.
// ---------------------------------------------------------------------------
__global__ __launch_bounds__(256) void k_gemm(const float* __restrict__ x,
    const __bf16* __restrict__ Bt, const float* __restrict__ bs,
    const float* __restrict__ aw, int N,
    __bf16* __restrict__ F, float* __restrict__ a_sT, float* __restrict__ a_dT)
{
    const int t    = threadIdx.x;
    const int w    = t >> 6;          // wave id == head id == col block
    const int lane = t & 63;
    const int c15  = lane & 15;
    const int quad = lane >> 4;
    const int n0   = blockIdx.x * 64;
    const int kq   = quad * 8;

    f32x4 acc[4][4] = {};
    const __bf16* BtW = Bt + (size_t)(w * 64) * 256;

    const bool full = (n0 + 64 <= N);

    #pragma unroll
    for (int k0 = 0; k0 < DIN; k0 += 32) {
        bf16x8 afr[4], bfr[4];
        #pragma unroll
        for (int rt = 0; rt < 4; ++rt) {
            const int row = n0 + rt * 16 + c15;
            float4 x0 = make_float4(0.f, 0.f, 0.f, 0.f), x1 = x0;
            if (full || row < N) {
                const float* xp = &x[(size_t)row * DIN + k0 + kq];
                x0 = *(const float4*)xp;
                x1 = *(const float4*)(xp + 4);
            }
            bf16x8 a;
            a[0] = (__bf16)x0.x; a[1] = (__bf16)x0.y;
            a[2] = (__bf16)x0.z; a[3] = (__bf16)x0.w;
            a[4] = (__bf16)x1.x; a[5] = (__bf16)x1.y;
            a[6] = (__bf16)x1.z; a[7] = (__bf16)x1.w;
            afr[rt] = a;
        }
        #pragma unroll
        for (int ct = 0; ct < 4; ++ct)
            bfr[ct] = *(const bf16x8*)&BtW[(size_t)(ct * 16 + c15) * 256 + k0 + kq];
        #pragma unroll
        for (int rt = 0; rt < 4; ++rt)
            #pragma unroll
            for (int ct = 0; ct < 4; ++ct)
                acc[rt][ct] = __builtin_amdgcn_mfma_f32_16x16x32_bf16(
                    afr[rt], bfr[ct], acc[rt][ct], 0, 0, 0);
    }

    const int h = w;
    float bsv[4], awsv[4], awdv[4];
    #pragma unroll
    for (int ct = 0; ct < 4; ++ct) {
        const int col = ct * 16 + c15;
        bsv[ct]  = bs[w * 64 + col];
        awsv[ct] = aw[h * AWS + col];
        awdv[ct] = aw[h * AWS + O + col];
    }

    #pragma unroll
    for (int rt = 0; rt < 4; ++rt) {
        float psum[4] = {0.f, 0.f, 0.f, 0.f};
        float pdum[4] = {0.f, 0.f, 0.f, 0.f};
        #pragma unroll
        for (int ct = 0; ct < 4; ++ct) {
            #pragma unroll
            for (int reg = 0; reg < 4; ++reg) {
                const float f = acc[rt][ct][reg] + bsv[ct];
                const int row = n0 + rt * 16 + quad * 4 + reg;
                if (row < N)
                    F[(size_t)row * HO + w * 64 + ct * 16 + c15] = (__bf16)f;
                psum[reg] = fmaf(f, awsv[ct], psum[reg]);
                pdum[reg] = fmaf(f, awdv[ct], pdum[reg]);
            }
        }
        #pragma unroll
        for (int reg = 0; reg < 4; ++reg) {
            float v = psum[reg], u = pdum[reg];
            #pragma unroll
            for (int off = 1; off < 16; off <<= 1) {
                v += __shfl_xor(v, off, 64);
                u += __shfl_xor(u, off, 64);
            }
            const int row = n0 + rt * 16 + quad * 4 + reg;
            if (c15 == 0 && row < N) {
                a_sT[row * H + h] = v;
                a_dT[row * H + h] = u;
            }
        }
    }
}

// ---------------------------------------------------------------------------
// Scan phase 1: block-local exclusive scan + block totals.
// row_ptr holds LOCAL prefixes; global offset bsum[i>>8] added at use.
// ---------------------------------------------------------------------------
__global__ __launch_bounds__(256) void k_scan1(const int* __restrict__ cnt,
    int* __restrict__ row_ptr, int* __restrict__ bsum, int N)
{
    __shared__ int wsum[4], woff[4];
    const int t = threadIdx.x, b = blockIdx.x;
    const int i = b * 256 + t;
    const int lane = t & 63, w = t >> 6;

    const int v = (i < N) ? cnt[i] : 0;
    int s = v;
    #pragma unroll
    for (int off = 1; off < 64; off <<= 1) {
        int u = __shfl_up(s, off, 64);
        if (lane >= off) s += u;
    }
    if (lane == 63) wsum[w] = s;
    __syncthreads();
    if (t == 0) {
        int run = 0;
        #pragma unroll
        for (int j = 0; j < 4; ++j) { woff[j] = run; run += wsum[j]; }
        bsum[b] = run;
    }
    __syncthreads();
    const int excl = s - v + woff[w];
    if (i < N) row_ptr[i] = excl;
    if (i == N - 1) row_ptr[N] = excl + v;
}

// ---------------------------------------------------------------------------
// Scan phase 2: single block, exclusive scan of bsum[0..nb) in place.
// ---------------------------------------------------------------------------
__global__ __launch_bounds__(256) void k_scan2(int* __restrict__ bsum, int nb)
{
    __shared__ int wsum[4], woff[4];
    const int t = threadIdx.x;
    const int lane = t & 63, w = t >> 6;

    const int v = (t < nb) ? bsum[t] : 0;
    int s = v;
    #pragma unroll
    for (int off = 1; off < 64; off <<= 1) {
        int u = __shfl_up(s, off, 64);
        if (lane >= off) s += u;
    }
    if (lane == 63) wsum[w] = s;
    __syncthreads();
    if (t == 0) {
        int run = 0;
        #pragma unroll
        for (int j = 0; j < 4; ++j) { woff[j] = run; run += wsum[j]; }
    }
    __syncthreads();
    const int excl = s - v + woff[w];
    __syncthreads();
    if (t < nb) bsum[t] = excl;
    if (t == 0) bsum[nb] = woff[3] + wsum[3];
}

// ---------------------------------------------------------------------------
// Scatter, atomic-free: pos = row_ptr[s] + bsum[s>>8] + rank[e].
// ---------------------------------------------------------------------------
__global__ __launch_bounds__(256) void k_scatter(const int* __restrict__ idx,
    const float* __restrict__ elem, const int* __restrict__ rank,
    const int* __restrict__ row_ptr, const int* __restrict__ bsum, int E,
    int2* __restrict__ csr)
{
    int e = blockIdx.x * 256 + threadIdx.x;
    if (e >= E) return;
    const int s = idx[e];
    const int d = idx[E + e];
    const int pos = row_ptr[s] + bsum[s >> 8] + rank[e];
    csr[pos] = make_int2(d, __float_as_int(elem[e]));
}

// ---------------------------------------------------------------------------
// Gather: 4 waves/block, one node per wave, no block barriers (wave-private
// LDS + lockstep wave => lgkmcnt fence suffices). Staging lane computes all
// 4 head weights for its edge; j-loop unrolled x4 for MLP.
// ---------------------------------------------------------------------------
__global__ __launch_bounds__(256) void k_gather(const int* __restrict__ row_ptr,
    const int* __restrict__ bsum, const int2* __restrict__ csr,
    const float* __restrict__ a_sT, const float* __restrict__ a_dT,
    const float* __restrict__ aw, const float* __restrict__ ab,
    const __bf16* __restrict__ F, float* __restrict__ out, int N)
{
    __shared__ int2  s_rec[4][64];
    __shared__ float s_w[4][256];

    const int t    = threadIdx.x;
    const int wv   = t >> 6;
    const int lane = t & 63;
    const int n    = blockIdx.x * 4 + wv;
    if (n >= N) return;
    const int h16  = lane >> 4;

    const int beg = row_ptr[n]     + bsum[n >> 8];
    const int end = row_ptr[n + 1] + bsum[(n + 1) >> 8];

    const float4 as4 = *(const float4*)&a_sT[n * 4];
    const float4 ab4 = *(const float4*)&ab[0];
    const float4 awe4 = make_float4(aw[0 * AWS + 2 * O], aw[1 * AWS + 2 * O],
                                    aw[2 * AWS + 2 * O], aw[3 * AWS + 2 * O]);

    float4 acc = make_float4(0.f, 0.f, 0.f, 0.f);
    float  rs  = 0.f;
    const __bf16* __restrict__ Fl = F + lane * 4;

    for (int base = beg; base < end; base += 64) {
        const int cnt = min(64, end - base);
        if (lane < cnt) {
            const int2 r = csr[base + lane];
            s_rec[wv][lane] = r;
            const float el = __int_as_float(r.y);
            const float4 ad = *(const float4*)&a_dT[r.x * 4];
            float4 w4;
            w4.x = __expf(-fmaxf((as4.x + ad.x + awe4.x * el + ab4.x) * 0.05f, 0.f));
            w4.y = __expf(-fmaxf((as4.y + ad.y + awe4.y * el + ab4.y) * 0.05f, 0.f));
            w4.z = __expf(-fmaxf((as4.z + ad.z + awe4.z * el + ab4.z) * 0.05f, 0.f));
            w4.w = __expf(-fmaxf((as4.w + ad.w + awe4.w * el + ab4.w) * 0.05f, 0.f));
            *(float4*)&s_w[wv][lane * 4] = w4;
        }
        __threadfence_block();

        int j = 0;
        for (; j + 4 <= cnt; j += 4) {
            const int d0 = s_rec[wv][j + 0].x;
            const int d1 = s_rec[wv][j + 1].x;
            const int d2 = s_rec[wv][j + 2].x;
            const int d3 = s_rec[wv][j + 3].x;
            const float w0 = s_w[wv][(j + 0) * 4 + h16];
            const float w1 = s_w[wv][(j + 1) * 4 + h16];
            const float w2 = s_w[wv][(j + 2) * 4 + h16];
            const float w3 = s_w[wv][(j + 3) * 4 + h16];
            const ushort4 f0 = *(const ushort4*)&Fl[(size_t)d0 * HO];
            const ushort4 f1 = *(const ushort4*)&Fl[(size_t)d1 * HO];
            const ushort4 f2 = *(const ushort4*)&Fl[(size_t)d2 * HO];
            const ushort4 f3 = *(const ushort4*)&Fl[(size_t)d3 * HO];
            acc.x = fmaf(w0, bf2f(f0.x), acc.x);
            acc.y = fmaf(w0, bf2f(f0.y), acc.y);
            acc.z = fmaf(w0, bf2f(f0.z), acc.z);
            acc.w = fmaf(w0, bf2f(f0.w), acc.w);
            acc.x = fmaf(w1, bf2f(f1.x), acc.x);
            acc.y = fmaf(w1, bf2f(f1.y), acc.y);
            acc.z = fmaf(w1, bf2f(f1.z), acc.z);
            acc.w = fmaf(w1, bf2f(f1.w), acc.w);
            acc.x = fmaf(w2, bf2f(f2.x), acc.x);
            acc.y = fmaf(w2, bf2f(f2.y), acc.y);
            acc.z = fmaf(w2, bf2f(f2.z), acc.z);
            acc.w = fmaf(w2, bf2f(f2.w), acc.w);
            acc.x = fmaf(w3, bf2f(f3.x), acc.x);
            acc.y = fmaf(w3, bf2f(f3.y), acc.y);
            acc.z = fmaf(w3, bf2f(f3.z), acc.z);
            acc.w = fmaf(w3, bf2f(f3.w), acc.w);
            rs += w0 + w1 + w2 + w3;
        }
        for (; j < cnt; ++j) {
            const int d = s_rec[wv][j].x;
            const float w = s_w[wv][j * 4 + h16];
            const ushort4 fv = *(const ushort4*)&Fl[(size_t)d * HO];
            acc.x = fmaf(w, bf2f(fv.x), acc.x);
            acc.y = fmaf(w, bf2f(fv.y), acc.y);
            acc.z = fmaf(w, bf2f(fv.z), acc.z);
            acc.w = fmaf(w, bf2f(fv.w), acc.w);
            rs += w;
        }
    }

    const float inv = 1.f / rs;
    float4 o = make_float4(acc.x * inv, acc.y * inv, acc.z * inv, acc.w * inv);
    *(float4*)&out[(size_t)n * HO + lane * 4] = o;
}

extern "C" void kernel_launch(void* const* d_in, const int* in_sizes, int n_in,
                              void* d_out, int out_size, void* d_ws, size_t ws_size,
                              hipStream_t stream)
{
    const float* x    = (const float*)d_in[0];
    const int*   idx  = (const int*)d_in[1];
    const float* elem = (const float*)d_in[2];
    const float* Ws   = (const float*)d_in[3];
    const float* bs   = (const float*)d_in[4];
    const float* aw   = (const float*)d_in[5];
    const float* ab   = (const float*)d_in[6];

    const int N = in_sizes[0] / DIN;   // 50000
    const int E = in_sizes[1] / 2;     // 800000
    const int nb = (N + 255) / 256;    // scan blocks (196)

    // ws layout: F[N*256]{bf16} | a_sT[N*4] | a_dT[N*4] | cnt[N] |
    //            row_ptr[N+1] | rank[E] | bsum[nb+1] | csr[E]{int2} | Bt{bf16}
    __bf16* F      = (__bf16*)d_ws;
    float* a_sT    = (float*)(F + (size_t)N * HO);
    float* a_dT    = a_sT + (size_t)N * H;
    int*   cnt     = (int*)(a_dT + (size_t)N * H);
    int*   row_ptr = cnt + N;
    int*   rank    = row_ptr + (N + 1);
    int*   bsum    = rank + E;
    size_t off = (size_t)((char*)(bsum + nb + 1) - (char*)d_ws);
    off = (off + 7) & ~(size_t)7;
    int2*  csr     = (int2*)((char*)d_ws + off);
    __bf16* Bt     = (__bf16*)(csr + E);
    float* out     = (float*)d_out;

    k_prep<<<256 + nb, 256, 0, stream>>>(Ws, Bt, cnt, N);
    k_hist<<<(E + 255) / 256, 256, 0, stream>>>(idx, E, cnt, rank);
    k_gemm<<<(N + 63) / 64, 256, 0, stream>>>(x, Bt, bs, aw, N, F, a_sT, a_dT);
    k_scan1<<<nb, 256, 0, stream>>>(cnt, row_ptr, bsum, N);
    k_scan2<<<1, 256, 0, stream>>>(bsum, nb);
    k_scatter<<<(E + 255) / 256, 256, 0, stream>>>(idx, elem, rank, row_ptr,
                                                   bsum, E, csr);
    k_gather<<<(N + 3) / 4, 256, 0, stream>>>(row_ptr, bsum, csr, a_sT, a_dT,
                                              aw, ab, F, out, N);
}